// Round 9
// baseline (464.641 us; speedup 1.0000x reference)
//
#include <hip/hip_runtime.h>

#define DIM  128
#define BINS 1024

typedef __attribute__((ext_vector_type(8))) short bf16x8;
typedef __attribute__((ext_vector_type(4))) float f32x4;

#define MFMA(a, b, c) __builtin_amdgcn_mfma_f32_16x16x32_bf16(a, b, c, 0, 0, 0)

#define GLDS(gp, lp) __builtin_amdgcn_global_load_lds(                        \
    (const __attribute__((address_space(1))) void*)(gp),                     \
    (__attribute__((address_space(3))) void*)(lp), 16, 0, 0)

// round-to-nearest-even fp32 -> bf16 bits (no NaN/Inf in this data)
__device__ __forceinline__ unsigned short rne16(float f) {
    unsigned u = __float_as_uint(f);
    unsigned r = u + 0x7FFFu + ((u >> 16) & 1u);
    return (unsigned short)(r >> 16);
}

// branchless top-2 insert, strict > (first-wins with ascending insert order)
__device__ __forceinline__ void ins2(float d, int b,
                                     float& d0, int& b0, float& d1, int& b1) {
    bool c1 = d > d1;
    float nd1 = c1 ? d : d1; int nb1 = c1 ? b : b1;
    bool c0 = nd1 > d0;
    d1 = c0 ? d0 : nd1;  b1 = c0 ? b0 : nb1;
    d0 = c0 ? nd1 : d0;  b0 = c0 ? nb1 : b0;
}

// ---- prep: esq (round-1 1-chain fmaf) + E -> swizzled bf16 hi/lo tables ----
__global__ __launch_bounds__(256) void vq_prep(
    const float* __restrict__ embed, unsigned short* __restrict__ ehs,
    unsigned short* __restrict__ els, float* __restrict__ esq_g)
{
    int b = blockIdx.x * 256 + threadIdx.x;  // grid exactly BINS/256
    const float* e = embed + (size_t)b * DIM;
    float s = 0.f;
    #pragma unroll
    for (int k = 0; k < DIM; ++k) s = fmaf(e[k], e[k], s);
    esq_g[b] = s;
    #pragma unroll
    for (int c = 0; c < 16; ++c) {          // 16B chunks of the bf16 row
        int slot = c ^ (b & 15);            // XOR-swizzle baked into storage
        #pragma unroll
        for (int j = 0; j < 8; ++j) {
            float f = e[c * 8 + j];
            unsigned short hb = rne16(f);
            float hf = __uint_as_float((unsigned)hb << 16);
            unsigned short lb = rne16(f - hf);
            ehs[b * 128 + slot * 8 + j] = hb;
            els[b * 128 + slot * 8 + j] = lb;
        }
    }
}

// ---- stage A: MFMA approx distances + per-row top-2 GROUPS (of 4 bins) ----
// Block: 256 thr = 4 waves; wave owns 64 rows (4 rowsets of 16).
// Per (tl,s): read eh+el once, feed 12 MFMAs (eh 8x, el 4x reuse) -> E LDS
// traffic per row halved vs round 8 (was LDS-BW-bound).
__global__ __launch_bounds__(256, 2) void vq_stage_a(
    const float* __restrict__ x,
    const unsigned short* __restrict__ ehs_g,
    const unsigned short* __restrict__ els_g,
    const float* __restrict__ esq_g,
    float* __restrict__ cand)               // [N][2] candidate GROUP bases
{
    __shared__ unsigned short ehb[2][8192];  // 2 x 16 KB (64 bins x 128 bf16)
    __shared__ unsigned short elb[2][8192];
    __shared__ float esq_lds[BINS];          // 4 KB

    const int tid = threadIdx.x;
    const int li  = tid & 15;        // x-row within rowset / bin row in tile
    const int g   = (tid >> 4) & 3;  // k-chunk group
    const int w   = tid >> 6;        // wave id (0..3)

    // ---- load + convert this lane's X chunks (rows rowA + rs*16) ----
    bf16x8 xh[4][4], xl[4][4];       // 128 VGPR, constant-indexed (rule #20)
    const size_t rowA = (size_t)blockIdx.x * 256 + w * 64 + li;
    #pragma unroll
    for (int rs = 0; rs < 4; ++rs) {
        const float* xp = x + (rowA + rs * 16) * DIM + g * 8;
        #pragma unroll
        for (int s = 0; s < 4; ++s) {
            float4 v0 = *(const float4*)(xp + s * 32);
            float4 v1 = *(const float4*)(xp + s * 32 + 4);
            float f[8] = {v0.x, v0.y, v0.z, v0.w, v1.x, v1.y, v1.z, v1.w};
            bf16x8 h, lo;
            #pragma unroll
            for (int j = 0; j < 8; ++j) {
                unsigned short hb = rne16(f[j]);
                h[j] = (short)hb;
                float hf = __uint_as_float((unsigned)hb << 16);
                lo[j] = (short)rne16(f[j] - hf);
            }
            xh[rs][s] = h; xl[rs][s] = lo;
        }
    }

    // staging: 2 tables x 16KB by 256 threads = 4 GLDS x 16B each per table
#define STAGE(stp_, buf_) do {                                                \
        const char* gE_ = (const char*)ehs_g + (size_t)(stp_) * 16384;        \
        const char* gL_ = (const char*)els_g + (size_t)(stp_) * 16384;        \
        char* lE_ = (char*)&ehb[buf_][0];                                     \
        char* lL_ = (char*)&elb[buf_][0];                                     \
        _Pragma("unroll")                                                     \
        for (int j_ = 0; j_ < 4; ++j_) {                                      \
            int o_ = tid * 16 + j_ * 4096;                                    \
            GLDS(gE_ + o_, lE_ + o_);                                         \
            GLDS(gL_ + o_, lL_ + o_);                                         \
        }                                                                     \
    } while (0)

    // ---- prologue: esq + slab 0 ----
    GLDS((const char*)esq_g + tid * 16, (char*)esq_lds + tid * 16);
    STAGE(0, 0);
    asm volatile("s_waitcnt vmcnt(0)" ::: "memory");
    __syncthreads();

    float d0[4], d1[4]; int b0[4], b1[4];
    #pragma unroll
    for (int rs = 0; rs < 4; ++rs) {
        d0[rs] = -3.402823466e38f; d1[rs] = -3.402823466e38f;
        b0[rs] = 0; b1[rs] = 0;
    }

    // fragment address: row (tl*16+li) at tl*4096+li*256; chunk (g+4s) at
    // slot ((g+4s)^li)*16  (matches vq_prep's c ^ (b&15) since bin&15 == li)
#define LDE(tl_, s_) (*(const bf16x8*)(bE + (tl_) * 4096 + li * 256 + (((g + 4 * (s_)) ^ li) << 4)))
#define LDL(tl_, s_) (*(const bf16x8*)(bL + (tl_) * 4096 + li * 256 + (((g + 4 * (s_)) ^ li) << 4)))

    for (int stp = 0; stp < 16; ++stp) {     // 16 steps x 64 bins
        const int buf = stp & 1;
        if (stp < 15) STAGE(stp + 1, buf ^ 1);   // prefetch next 64-bin slab
        const char* bE = (const char*)&ehb[buf][0];
        const char* bL = (const char*)&elb[buf][0];

        // software-pipelined fragment loads across (tl, s)
        bf16x8 ehc = LDE(0, 0), elc = LDL(0, 0);
        #pragma unroll
        for (int tl = 0; tl < 4; ++tl) {
            f32x4 aP[4], aQa[4], aQb[4];     // 12 independent chains
            #pragma unroll
            for (int rs = 0; rs < 4; ++rs) {
                aP[rs]  = f32x4{0.f,0.f,0.f,0.f};
                aQa[rs] = f32x4{0.f,0.f,0.f,0.f};
                aQb[rs] = f32x4{0.f,0.f,0.f,0.f};
            }
            #pragma unroll
            for (int s = 0; s < 4; ++s) {
                bf16x8 ehn = ehc, eln = elc;
                int ns = s + 1, ntl = tl;
                if (ns == 4) { ns = 0; ntl = tl + 1; }
                if (ntl < 4) { ehn = LDE(ntl, ns); eln = LDL(ntl, ns); }
                #pragma unroll
                for (int rs = 0; rs < 4; ++rs) {
                    aP[rs]  = MFMA(ehc, xh[rs][s], aP[rs]);
                    aQa[rs] = MFMA(elc, xh[rs][s], aQa[rs]);
                    aQb[rs] = MFMA(ehc, xl[rs][s], aQb[rs]);
                }
                ehc = ehn; elc = eln;
            }
            // group fold: key = 2*dot - esq; group-of-4 max tree + one ins2
            const int binb = stp * 64 + tl * 16 + g * 4;   // group base
            const f32x4 eq = *(const f32x4*)&esq_lds[binb];
            #pragma unroll
            for (int rs = 0; rs < 4; ++rs) {
                float k0 = fmaf(2.f, (aP[rs][0] + aQa[rs][0]) + aQb[rs][0], -eq[0]);
                float k1 = fmaf(2.f, (aP[rs][1] + aQa[rs][1]) + aQb[rs][1], -eq[1]);
                float k2 = fmaf(2.f, (aP[rs][2] + aQa[rs][2]) + aQb[rs][2], -eq[2]);
                float k3 = fmaf(2.f, (aP[rs][3] + aQa[rs][3]) + aQb[rs][3], -eq[3]);
                float gm = fmaxf(fmaxf(k0, k1), fmaxf(k2, k3));
                ins2(gm, binb, d0[rs], b0[rs], d1[rs], b1[rs]);
            }
        }
        asm volatile("s_waitcnt vmcnt(0)" ::: "memory");
        __syncthreads();
    }
#undef LDE
#undef LDL
#undef STAGE

    // ---- merge the 4 k-groups (disjoint group sets, same rows) ----
    #pragma unroll
    for (int mm = 16; mm <= 32; mm <<= 1) {
        #pragma unroll
        for (int rs = 0; rs < 4; ++rs) {
            float pd0 = __shfl_xor(d0[rs], mm); int pb0 = __shfl_xor(b0[rs], mm);
            float pd1 = __shfl_xor(d1[rs], mm); int pb1 = __shfl_xor(b1[rs], mm);
            ins2(pd0, pb0, d0[rs], b0[rs], d1[rs], b1[rs]);
            ins2(pd1, pb1, d0[rs], b0[rs], d1[rs], b1[rs]);
        }
    }
    if ((tid & 63) < 16) {
        #pragma unroll
        for (int rs = 0; rs < 4; ++rs) {
            cand[(rowA + rs * 16) * 2 + 0] = (float)b0[rs];
            cand[(rowA + rs * 16) * 2 + 1] = (float)b1[rs];
        }
    }
}

// ---- rescore: exact fp32 on 2 groups x 4 bins, float4 e-loads, k-outer ----
// Chain split = k mod 4 and (a0+a1)+(a2+a3) combine: bit-identical to round 1.
__global__ __launch_bounds__(256) void vq_rescore(
    const float* __restrict__ x, const float* __restrict__ embed,
    const float* __restrict__ esq_g, const float* __restrict__ cand,
    float* __restrict__ ind_f)
{
    __shared__ float xsm[256 * 129];         // 129-stride: conflict-free rows
    const int tid = threadIdx.x;
    const size_t base = (size_t)blockIdx.x * 256;
    const float4* xg = (const float4*)(x + base * DIM);
    #pragma unroll
    for (int i = 0; i < 32; ++i) {
        int idx = tid + 256 * i;
        int r = idx >> 5, c4 = idx & 31;
        float4 v = xg[idx];
        float* dst = &xsm[r * 129 + c4 * 4];
        dst[0] = v.x; dst[1] = v.y; dst[2] = v.z; dst[3] = v.w;
    }
    __syncthreads();

    const float* xr = &xsm[tid * 129];
    float xsq = 0.f;
    #pragma unroll
    for (int k = 0; k < DIM; ++k) xsq = fmaf(xr[k], xr[k], xsq);

    const size_t row = base + tid;
    const int gb0 = (int)cand[row * 2], gb1 = (int)cand[row * 2 + 1];
    int bins[8];
    #pragma unroll
    for (int r = 0; r < 4; ++r) { bins[r] = gb0 + r; bins[4 + r] = gb1 + r; }

    f32x4 acc[8];
    #pragma unroll
    for (int c = 0; c < 8; ++c) acc[c] = f32x4{0.f,0.f,0.f,0.f};
    const float4* e4 = (const float4*)embed;
    #pragma unroll 4
    for (int q = 0; q < 32; ++q) {           // k-chunk of 4
        float4 xv = *(const float4*)&xr[q * 4];
        #pragma unroll
        for (int c = 0; c < 8; ++c) {
            float4 ev = e4[(size_t)bins[c] * 32 + q];
            acc[c][0] = fmaf(xv.x, ev.x, acc[c][0]);
            acc[c][1] = fmaf(xv.y, ev.y, acc[c][1]);
            acc[c][2] = fmaf(xv.z, ev.z, acc[c][2]);
            acc[c][3] = fmaf(xv.w, ev.w, acc[c][3]);
        }
    }
    float bd = -3.402823466e38f;
    int   bb = 0x7FFFFFFF;
    #pragma unroll
    for (int c = 0; c < 8; ++c) {
        float dot = (acc[c][0] + acc[c][1]) + (acc[c][2] + acc[c][3]);
        float d = -(fmaf(-2.f, dot, xsq) + esq_g[bins[c]]);  // round-1 expr
        if (d > bd || (d == bd && bins[c] < bb)) { bd = d; bb = bins[c]; }
    }
    ind_f[row] = (float)bb;
}

// ---- gather: quantize = embed[ind], coalesced float4 ----
__global__ __launch_bounds__(256) void vq_gather(
    const float* __restrict__ embed,
    const float* __restrict__ ind_f,
    float4* __restrict__ out)
{
    int i   = blockIdx.x * 256 + threadIdx.x;   // over N*DIM/4
    int row = i >> 5;                           // DIM/4 == 32
    int k   = i & 31;
    int b   = (int)ind_f[row];
    out[i] = reinterpret_cast<const float4*>(embed)[b * (DIM / 4) + k];
}

extern "C" void kernel_launch(void* const* d_in, const int* in_sizes, int n_in,
                              void* d_out, int out_size, void* d_ws, size_t ws_size,
                              hipStream_t stream) {
    const float* x     = (const float*)d_in[0];   // [N, 128] fp32
    const float* embed = (const float*)d_in[1];   // [1024, 128] fp32
    float* out = (float*)d_out;

    const int N = in_sizes[0] / DIM;              // 262144
    float* ind_f = out + (size_t)N * DIM;         // output 1 (indices as float)

    // scratch carved out of the quantize region (fully overwritten by gather):
    char* ob = (char*)d_out;
    float* cand = out;                                        // [N][2] floats (2 MB)
    unsigned short* ehs = (unsigned short*)(ob + (32u << 20)); // 256 KB
    unsigned short* els = (unsigned short*)(ob + (34u << 20)); // 256 KB
    float* esq_g        = (float*)(ob + (36u << 20));          // 4 KB

    vq_prep<<<BINS / 256, 256, 0, stream>>>(embed, ehs, els, esq_g);
    vq_stage_a<<<N / 256, 256, 0, stream>>>(x, ehs, els, esq_g, cand);
    vq_rescore<<<N / 256, 256, 0, stream>>>(x, embed, esq_g, cand, ind_f);
    vq_gather<<<(N * (DIM / 4)) / 256, 256, 0, stream>>>(embed, ind_f, (float4*)out);
}

// Round 10
// 361.117 us; speedup vs baseline: 1.2867x; 1.2867x over previous
//
#include <hip/hip_runtime.h>

#define DIM  128
#define BINS 1024

typedef __attribute__((ext_vector_type(8))) short bf16x8;
typedef __attribute__((ext_vector_type(4))) float f32x4;

#define MFMA(a, b, c) __builtin_amdgcn_mfma_f32_16x16x32_bf16(a, b, c, 0, 0, 0)

#define GLDS(gp, lp) __builtin_amdgcn_global_load_lds(                        \
    (const __attribute__((address_space(1))) void*)(gp),                     \
    (__attribute__((address_space(3))) void*)(lp), 16, 0, 0)

// round-to-nearest-even fp32 -> bf16 bits (no NaN/Inf in this data)
__device__ __forceinline__ unsigned short rne16(float f) {
    unsigned u = __float_as_uint(f);
    unsigned r = u + 0x7FFFu + ((u >> 16) & 1u);
    return (unsigned short)(r >> 16);
}

// branchless top-2 insert, strict > (first-wins with ascending insert order)
__device__ __forceinline__ void ins2(float d, int b,
                                     float& d0, int& b0, float& d1, int& b1) {
    bool c1 = d > d1;
    float nd1 = c1 ? d : d1; int nb1 = c1 ? b : b1;
    bool c0 = nd1 > d0;
    d1 = c0 ? d0 : nd1;  b1 = c0 ? b0 : nb1;
    d0 = c0 ? nd1 : d0;  b0 = c0 ? nb1 : b0;
}

// ---- prep: esq (round-1 1-chain fmaf) + E -> swizzled bf16 hi/lo tables ----
__global__ __launch_bounds__(256) void vq_prep(
    const float* __restrict__ embed, unsigned short* __restrict__ ehs,
    unsigned short* __restrict__ els, float* __restrict__ esq_g)
{
    int b = blockIdx.x * 256 + threadIdx.x;  // grid exactly BINS/256
    const float* e = embed + (size_t)b * DIM;
    float s = 0.f;
    #pragma unroll
    for (int k = 0; k < DIM; ++k) s = fmaf(e[k], e[k], s);
    esq_g[b] = s;
    #pragma unroll
    for (int c = 0; c < 16; ++c) {          // 16B chunks of the bf16 row
        int slot = c ^ (b & 15);            // XOR-swizzle baked into storage
        #pragma unroll
        for (int j = 0; j < 8; ++j) {
            float f = e[c * 8 + j];
            unsigned short hb = rne16(f);
            float hf = __uint_as_float((unsigned)hb << 16);
            unsigned short lb = rne16(f - hf);
            ehs[b * 128 + slot * 8 + j] = hb;
            els[b * 128 + slot * 8 + j] = lb;
        }
    }
}

// ---- stage A: round-8 numerics, m201-style phase schedule ----
// 512 thr = 8 waves, wave owns 32 rows (2 rowsets). 16 steps x 64 bins.
// Per step: 2 sync-phases; counted vmcnt(2) keeps next-slab GLDS in flight
// across barriers; per tile: 8 ds_read -> lgkmcnt(0)+sched_barrier ->
// setprio(1) 24 MFMA setprio(0) -> group fold.
__global__ __launch_bounds__(512, 2) void vq_stage_a(
    const float* __restrict__ x,
    const unsigned short* __restrict__ ehs_g,
    const unsigned short* __restrict__ els_g,
    const float* __restrict__ esq_g,
    float* __restrict__ cand)               // [N][2] candidate GROUP bases
{
    __shared__ unsigned short ehb[2][8192];  // 2 x 16 KB (64 bins x 128 bf16)
    __shared__ unsigned short elb[2][8192];
    __shared__ float esq_lds[BINS];          // 4 KB

    const int tid = threadIdx.x;
    const int li  = tid & 15;
    const int g   = (tid >> 4) & 3;
    const int w   = tid >> 6;

    // X fragments (rows rowA, rowA+16), bf16 hi/lo — 64 VGPR, const-indexed
    bf16x8 xh[2][4], xl[2][4];
    const size_t rowA = (size_t)blockIdx.x * 256 + w * 32 + li;
    #pragma unroll
    for (int rs = 0; rs < 2; ++rs) {
        const float* xp = x + (rowA + rs * 16) * DIM + g * 8;
        #pragma unroll
        for (int s = 0; s < 4; ++s) {
            float4 v0 = *(const float4*)(xp + s * 32);
            float4 v1 = *(const float4*)(xp + s * 32 + 4);
            float f[8] = {v0.x, v0.y, v0.z, v0.w, v1.x, v1.y, v1.z, v1.w};
            bf16x8 h, lo;
            #pragma unroll
            for (int j = 0; j < 8; ++j) {
                unsigned short hb = rne16(f[j]);
                h[j] = (short)hb;
                float hf = __uint_as_float((unsigned)hb << 16);
                lo[j] = (short)rne16(f[j] - hf);
            }
            xh[rs][s] = h; xl[rs][s] = lo;
        }
    }

    // ---- prologue: esq + slab 0 (4 GLDS), full drain once ----
    esq_lds[tid] = esq_g[tid];
    esq_lds[tid + 512] = esq_g[tid + 512];
    {
        int o = tid * 16;
        GLDS((const char*)ehs_g + o,        (char*)&ehb[0][0] + o);
        GLDS((const char*)ehs_g + o + 8192, (char*)&ehb[0][0] + o + 8192);
        GLDS((const char*)els_g + o,        (char*)&elb[0][0] + o);
        GLDS((const char*)els_g + o + 8192, (char*)&elb[0][0] + o + 8192);
    }
    asm volatile("s_waitcnt vmcnt(0)" ::: "memory");
    __syncthreads();

    float d0[2], d1[2]; int b0[2], b1[2];
    #pragma unroll
    for (int rs = 0; rs < 2; ++rs) {
        d0[rs] = -3.402823466e38f; d1[rs] = -3.402823466e38f;
        b0[rs] = 0; b1[rs] = 0;
    }

#define LDE(tl_, s_) (*(const bf16x8*)(bE + (tl_) * 4096 + li * 256 + (((g + 4 * (s_)) ^ li) << 4)))
#define LDL(tl_, s_) (*(const bf16x8*)(bL + (tl_) * 4096 + li * 256 + (((g + 4 * (s_)) ^ li) << 4)))
#define MSTEP(EH, EL, S)                                                      \
    aP0  = MFMA(EH, xh[0][S], aP0);  aP1  = MFMA(EH, xh[1][S], aP1);          \
    aQa0 = MFMA(EL, xh[0][S], aQa0); aQa1 = MFMA(EL, xh[1][S], aQa1);         \
    aQb0 = MFMA(EH, xl[0][S], aQb0); aQb1 = MFMA(EH, xl[1][S], aQb1);

    for (int stp = 0; stp < 16; ++stp) {
        const int buf = stp & 1;
        const char* bE = (const char*)&ehb[buf][0];
        const char* bL = (const char*)&elb[buf][0];
        char* nE = (char*)&ehb[buf ^ 1][0];
        char* nL = (char*)&elb[buf ^ 1][0];
        const char* gE = (const char*)ehs_g + (size_t)(stp + 1) * 16384;
        const char* gL = (const char*)els_g + (size_t)(stp + 1) * 16384;

        #pragma unroll
        for (int ph = 0; ph < 2; ++ph) {
            // tiles 2ph,2ph+1 staged by pair issued at (stp-1, ph);
            // exactly one newer pair outstanding -> vmcnt(2).
            if (stp == 15 && ph == 1) asm volatile("s_waitcnt vmcnt(0)" ::: "memory");
            else                      asm volatile("s_waitcnt vmcnt(2)" ::: "memory");
            __builtin_amdgcn_s_barrier();
            if (stp < 15) {                 // prefetch same half of next slab
                int o = tid * 16 + ph * 8192;
                GLDS(gE + o, nE + o);
                GLDS(gL + o, nL + o);
            }
            #pragma unroll
            for (int ti = 0; ti < 2; ++ti) {
                const int tl = ph * 2 + ti;
                f32x4 aP0  = {0.f,0.f,0.f,0.f}, aP1  = {0.f,0.f,0.f,0.f};
                f32x4 aQa0 = {0.f,0.f,0.f,0.f}, aQa1 = {0.f,0.f,0.f,0.f};
                f32x4 aQb0 = {0.f,0.f,0.f,0.f}, aQb1 = {0.f,0.f,0.f,0.f};
                bf16x8 eh0 = LDE(tl, 0), eh1 = LDE(tl, 1);
                bf16x8 eh2 = LDE(tl, 2), eh3 = LDE(tl, 3);
                bf16x8 el0 = LDL(tl, 0), el1 = LDL(tl, 1);
                bf16x8 el2 = LDL(tl, 2), el3 = LDL(tl, 3);
                asm volatile("s_waitcnt lgkmcnt(0)" ::: "memory");
                __builtin_amdgcn_sched_barrier(0);   // rule 18
                __builtin_amdgcn_s_setprio(1);
                MSTEP(eh0, el0, 0); MSTEP(eh1, el1, 1);
                MSTEP(eh2, el2, 2); MSTEP(eh3, el3, 3);
                __builtin_amdgcn_s_setprio(0);
                // group fold: key = 2*dot - esq; group max + one ins2
                const int binb = stp * 64 + tl * 16 + g * 4;
                const f32x4 eq = *(const f32x4*)&esq_lds[binb];
                {
                    float k0 = fmaf(2.f, (aP0[0] + aQa0[0]) + aQb0[0], -eq[0]);
                    float k1 = fmaf(2.f, (aP0[1] + aQa0[1]) + aQb0[1], -eq[1]);
                    float k2 = fmaf(2.f, (aP0[2] + aQa0[2]) + aQb0[2], -eq[2]);
                    float k3 = fmaf(2.f, (aP0[3] + aQa0[3]) + aQb0[3], -eq[3]);
                    float gm = fmaxf(fmaxf(k0, k1), fmaxf(k2, k3));
                    ins2(gm, binb, d0[0], b0[0], d1[0], b1[0]);
                }
                {
                    float k0 = fmaf(2.f, (aP1[0] + aQa1[0]) + aQb1[0], -eq[0]);
                    float k1 = fmaf(2.f, (aP1[1] + aQa1[1]) + aQb1[1], -eq[1]);
                    float k2 = fmaf(2.f, (aP1[2] + aQa1[2]) + aQb1[2], -eq[2]);
                    float k3 = fmaf(2.f, (aP1[3] + aQa1[3]) + aQb1[3], -eq[3]);
                    float gm = fmaxf(fmaxf(k0, k1), fmaxf(k2, k3));
                    ins2(gm, binb, d0[1], b0[1], d1[1], b1[1]);
                }
            }
        }
    }
#undef LDE
#undef LDL
#undef MSTEP

    // ---- merge the 4 k-groups (disjoint group sets, same rows) ----
    #pragma unroll
    for (int mm = 16; mm <= 32; mm <<= 1) {
        #pragma unroll
        for (int rs = 0; rs < 2; ++rs) {
            float pd0 = __shfl_xor(d0[rs], mm); int pb0 = __shfl_xor(b0[rs], mm);
            float pd1 = __shfl_xor(d1[rs], mm); int pb1 = __shfl_xor(b1[rs], mm);
            ins2(pd0, pb0, d0[rs], b0[rs], d1[rs], b1[rs]);
            ins2(pd1, pb1, d0[rs], b0[rs], d1[rs], b1[rs]);
        }
    }
    if ((tid & 63) < 16) {
        cand[rowA * 2 + 0] = (float)b0[0];
        cand[rowA * 2 + 1] = (float)b1[0];
        cand[(rowA + 16) * 2 + 0] = (float)b0[1];
        cand[(rowA + 16) * 2 + 1] = (float)b1[1];
    }
}

// ---- rescore: exact fp32, 4 lanes/row, 2 bins/lane full-K ----
// Per-bin chain = k mod 4 + (a0+a1)+(a2+a3), xsq single chain k ascending:
// bit-identical to the round-1-proven expression. No LDS, coalesced x.
__global__ __launch_bounds__(256) void vq_rescore(
    const float* __restrict__ x, const float* __restrict__ embed,
    const float* __restrict__ esq_g, const float* __restrict__ cand,
    float* __restrict__ ind_f)
{
    const int tid  = threadIdx.x;
    const int lane = tid & 63;
    const int sub  = tid & 3;
    const size_t row = (size_t)blockIdx.x * 64 + (tid >> 2);

    // my quarter of the row (coalesced float4)
    const float4* xg = (const float4*)(x + row * DIM);
    float4 xq[8];
    #pragma unroll
    for (int j = 0; j < 8; ++j) xq[j] = xg[sub * 8 + j];

    const int gb0 = (int)cand[row * 2], gb1 = (int)cand[row * 2 + 1];
    const int binA = (sub < 2 ? gb0 : gb1) + (sub & 1) * 2;
    const int binB = binA + 1;

    const float4* e4 = (const float4*)embed;
    f32x4 accA = {0.f,0.f,0.f,0.f}, accB = {0.f,0.f,0.f,0.f};
    float xs = 0.f;
    #pragma unroll
    for (int q = 0; q < 32; ++q) {
        const int src = (lane & ~3) | (q >> 3);
        float4 xv;
        xv.x = __shfl(xq[q & 7].x, src);
        xv.y = __shfl(xq[q & 7].y, src);
        xv.z = __shfl(xq[q & 7].z, src);
        xv.w = __shfl(xq[q & 7].w, src);
        xs = fmaf(xv.x, xv.x, xs); xs = fmaf(xv.y, xv.y, xs);
        xs = fmaf(xv.z, xv.z, xs); xs = fmaf(xv.w, xv.w, xs);
        float4 evA = e4[(size_t)binA * 32 + q];
        float4 evB = e4[(size_t)binB * 32 + q];
        accA[0] = fmaf(xv.x, evA.x, accA[0]); accA[1] = fmaf(xv.y, evA.y, accA[1]);
        accA[2] = fmaf(xv.z, evA.z, accA[2]); accA[3] = fmaf(xv.w, evA.w, accA[3]);
        accB[0] = fmaf(xv.x, evB.x, accB[0]); accB[1] = fmaf(xv.y, evB.y, accB[1]);
        accB[2] = fmaf(xv.z, evB.z, accB[2]); accB[3] = fmaf(xv.w, evB.w, accB[3]);
    }
    float dotA = (accA[0] + accA[1]) + (accA[2] + accA[3]);
    float dotB = (accB[0] + accB[1]) + (accB[2] + accB[3]);
    float dA = -(fmaf(-2.f, dotA, xs) + esq_g[binA]);   // round-1 expression
    float dB = -(fmaf(-2.f, dotB, xs) + esq_g[binB]);

    float bd = dA; int bb = binA;
    if (dB > bd || (dB == bd && binB < bb)) { bd = dB; bb = binB; }
    #pragma unroll
    for (int m = 1; m <= 2; m <<= 1) {      // quad-local (d, bin) argmax
        float pd = __shfl_xor(bd, m);
        int   pb = __shfl_xor(bb, m);
        if (pd > bd || (pd == bd && pb < bb)) { bd = pd; bb = pb; }
    }
    if (sub == 0) ind_f[row] = (float)bb;
}

// ---- gather: quantize = embed[ind], coalesced float4 ----
__global__ __launch_bounds__(256) void vq_gather(
    const float* __restrict__ embed,
    const float* __restrict__ ind_f,
    float4* __restrict__ out)
{
    int i   = blockIdx.x * 256 + threadIdx.x;   // over N*DIM/4
    int row = i >> 5;                           // DIM/4 == 32
    int k   = i & 31;
    int b   = (int)ind_f[row];
    out[i] = reinterpret_cast<const float4*>(embed)[b * (DIM / 4) + k];
}

extern "C" void kernel_launch(void* const* d_in, const int* in_sizes, int n_in,
                              void* d_out, int out_size, void* d_ws, size_t ws_size,
                              hipStream_t stream) {
    const float* x     = (const float*)d_in[0];   // [N, 128] fp32
    const float* embed = (const float*)d_in[1];   // [1024, 128] fp32
    float* out = (float*)d_out;

    const int N = in_sizes[0] / DIM;              // 262144
    float* ind_f = out + (size_t)N * DIM;         // output 1 (indices as float)

    // scratch carved out of the quantize region (fully overwritten by gather):
    char* ob = (char*)d_out;
    float* cand = out;                                        // [N][2] floats (2 MB)
    unsigned short* ehs = (unsigned short*)(ob + (32u << 20)); // 256 KB
    unsigned short* els = (unsigned short*)(ob + (34u << 20)); // 256 KB
    float* esq_g        = (float*)(ob + (36u << 20));          // 4 KB

    vq_prep<<<BINS / 256, 256, 0, stream>>>(embed, ehs, els, esq_g);
    vq_stage_a<<<N / 256, 512, 0, stream>>>(x, ehs, els, esq_g, cand);
    vq_rescore<<<N / 64, 256, 0, stream>>>(x, embed, esq_g, cand, ind_f);
    vq_gather<<<(N * (DIM / 4)) / 256, 256, 0, stream>>>(embed, ind_f, (float4*)out);
}